// Round 11
// baseline (126.898 us; speedup 1.0000x reference)
//
#include <hip/hip_runtime.h>
#include <math.h>

// MovingMaxMinHorizontal: causal max-filter(L=64) then min-filter(L=64) over
// [B=64, C=64, T=4096] f32 rows with -inf / +inf streaming-state left pads.
//
// Round-11: FULLY FUSED, wave-independent. No LDS, no barriers. Each 16-lane
// DPP row produces 64 outputs at base qA from 3 overlapping x slabs:
//   X0 = xpad[qA-63 .. qA], X1 = xpad[qA+1 .. qA+64], X2 = xpad[qA+65 .. qA+128]
//   midA = window_max(X0,X1) -> mpad slab @qA    (= mid[qA-63..qA], slab-aligned)
//   midB = window_max(X1,X2) -> mpad slab @qA+64
//   out  = window_min(midA,midB) -> out[qA .. qA+63]
// window chunk = within-lane serial scans (3 ops) + 16-lane row scans via DPP
// row_shl/row_shr 1,2,4,8 + exclusive shift with identity (verified r7/r10).
// Boundaries: slabs touching pads/tails use a clamped scalar path
// (p<0 -> -inf, p<63 -> prev_input, p>4158 -> -inf). Fake tail values never
// reach a valid output (excl-prefix[j] uses only a1[0..j-1]). The qA==0 slab
// is overridden with prev_max_out[0..62]; its element 63 = mid[0] falls out
// of the clamped scan automatically.

#define TT    4096
#define PADN  63
#define XPMAX 4158   // last valid xpad index (TT + PADN - 1)

// 4-byte-aligned float4 for unaligned-by-one global vector loads.
struct __attribute__((packed, aligned(4))) f4u { float x, y, z, w; };

template<int CTRL>
__device__ __forceinline__ float dpp_self(float v) {
  return __int_as_float(__builtin_amdgcn_update_dpp(
      __float_as_int(v), __float_as_int(v), CTRL, 0xF, 0xF, false));
}
template<int CTRL>
__device__ __forceinline__ float dpp_old(float oldv, float v) {
  return __int_as_float(__builtin_amdgcn_update_dpp(
      __float_as_int(oldv), __float_as_int(v), CTRL, 0xF, 0xF, false));
}

// 64-wide sliding window over [a0 | a1] for one 16-lane row: r[k] (k=0..3) =
// OP over window starting at j = 4*l16+k. (verified structure, rounds 7/10)
template<bool IS_MAX>
__device__ __forceinline__ void chunk_windows(float4 a0, float4 a1, float r[4]) {
  const float ID = IS_MAX ? -INFINITY : INFINITY;
#define OPF(x, y) (IS_MAX ? fmaxf((x), (y)) : fminf((x), (y)))
  // within-lane suffix scan of a0
  float s3 = a0.w;
  float s2 = OPF(a0.z, s3);
  float s1 = OPF(a0.y, s2);
  float s0 = OPF(a0.x, s1);
  // row inclusive suffix scan of lane totals (row_shl:d = lane i <- i+d)
  float t = s0;
  t = OPF(t, dpp_self<0x101>(t));
  t = OPF(t, dpp_self<0x102>(t));
  t = OPF(t, dpp_self<0x104>(t));
  t = OPF(t, dpp_self<0x108>(t));
  float E = dpp_old<0x101>(ID, t);   // exclusive lane-suffix (l16==15 -> ID)

  // within-lane prefix scan of a1
  float p0 = a1.x;
  float p1 = OPF(p0, a1.y);
  float p2 = OPF(p1, a1.z);
  float p3 = OPF(p2, a1.w);
  float u = p3;
  u = OPF(u, dpp_self<0x111>(u));    // row_shr:d = lane i <- i-d
  u = OPF(u, dpp_self<0x112>(u));
  u = OPF(u, dpp_self<0x114>(u));
  u = OPF(u, dpp_self<0x118>(u));
  float Ep = dpp_old<0x111>(ID, u);  // exclusive lane-prefix (l16==0 -> ID)

  r[0] = OPF(OPF(s0, E), Ep);
  r[1] = OPF(OPF(s1, E), OPF(Ep, p0));
  r[2] = OPF(OPF(s2, E), OPF(Ep, p1));
  r[3] = OPF(OPF(s3, E), OPF(Ep, p2));
#undef OPF
}

// xpad slab [t0 .. t0+63], this lane's 4 elems at t0 + 4*l16 .. +3.
__device__ __forceinline__ float4 load_slab(int t0, int l16,
                                            const float* __restrict__ xrow,
                                            const float* __restrict__ pirow) {
  if (t0 >= PADN && t0 <= TT - 1) {  // slab fully inside x
    f4u v = *reinterpret_cast<const f4u*>(xrow + t0 - PADN + 4 * l16);
    return make_float4(v.x, v.y, v.z, v.w);
  }
  float e[4];
  #pragma unroll
  for (int k = 0; k < 4; ++k) {
    const int q = t0 + 4 * l16 + k;
    float v;
    if (q < 0)           v = -INFINITY;     // before stream start
    else if (q < PADN)   v = pirow[q];      // prev_input pad
    else if (q <= XPMAX) v = xrow[q - PADN];
    else                 v = -INFINITY;     // past row end (never used)
    e[k] = v;
  }
  return make_float4(e[0], e[1], e[2], e[3]);
}

__global__ __launch_bounds__(256)
void mmh_kernel(const float* __restrict__ x,
                const float* __restrict__ prev_input,
                const float* __restrict__ prev_max_out,
                float* __restrict__ out)
{
    const int tid  = threadIdx.x;
    const int lane = tid & 63;
    const int wv   = tid >> 6;            // 0..3
    const int l16  = lane & 15;
    const int rrow = lane >> 4;           // 16-lane DPP row, 0..3

    const int row   = blockIdx.x >> 2;                    // [B*C] row
    const int wbase = ((blockIdx.x & 3) * 4 + wv) * 256;  // wave's output base
    const int qA    = wbase + 64 * rrow;                  // this row's chunk base

    const float* xrow  = x            + (size_t)row * TT;
    const float* pirow = prev_input   + (size_t)row * PADN;
    const float* pmrow = prev_max_out + (size_t)row * PADN;
    float*       orow  = out          + (size_t)row * TT;

    const float4 X0 = load_slab(qA - 63, l16, xrow, pirow);
    const float4 X1 = load_slab(qA + 1,  l16, xrow, pirow);
    const float4 X2 = load_slab(qA + 65, l16, xrow, pirow);

    float mA[4], mB[4];
    chunk_windows<true>(X0, X1, mA);   // mpad slab @qA
    chunk_windows<true>(X1, X2, mB);   // mpad slab @qA+64

    if (qA == 0) {
        // mpad[0..62] = prev_max_out; mpad[63] = mid[0] (already in mA[3], l16==15)
        #pragma unroll
        for (int k = 0; k < 4; ++k) {
            const int p = 4 * l16 + k;
            if (p < PADN) mA[k] = pmrow[p];
        }
    }

    const float4 a0 = make_float4(mA[0], mA[1], mA[2], mA[3]);
    const float4 a1 = make_float4(mB[0], mB[1], mB[2], mB[3]);
    float r[4];
    chunk_windows<false>(a0, a1, r);

    *reinterpret_cast<float4*>(orow + qA + 4 * l16) =
        make_float4(r[0], r[1], r[2], r[3]);
}

extern "C" void kernel_launch(void* const* d_in, const int* in_sizes, int n_in,
                              void* d_out, int out_size, void* d_ws, size_t ws_size,
                              hipStream_t stream) {
    const float* x            = (const float*)d_in[0];  // [64,64,4096]
    const float* prev_input   = (const float*)d_in[1];  // [64,64,63]
    const float* prev_max_out = (const float*)d_in[2];  // [64,64,63]
    float*       out          = (float*)d_out;          // [64,64,4096]

    // 4 blocks per row, 256 threads (4 waves); each wave = 256 outputs.
    mmh_kernel<<<64 * 64 * 4, 256, 0, stream>>>(x, prev_input, prev_max_out, out);
}

// Round 15
// 117.400 us; speedup vs baseline: 1.0809x; 1.0809x over previous
//
#include <hip/hip_runtime.h>
#include <math.h>

// MovingMaxMinHorizontal: causal max-filter(L=64) then min-filter(L=64) over
// [B=64, C=64, T=4096] f32 rows with -inf / +inf streaming-state left pads.
//
// Round-12: wave-independent (no LDS, no barriers) + slab-reuse marching.
// Each 16-lane DPP row owns a 512-output segment [S .. S+511] and marches 8
// consecutive 64-output chunks:
//   slabs  L_j = xpad[S-63+64j .. S+64j],            j = 0..9   (10 loads)
//   stage1 M_j = window_max(L_j, L_{j+1}) = mpad slab @(S+64j), j = 0..8
//   stage2 out chunk j = window_min(M_j, M_{j+1}),              j = 0..7
// Read amplification 1.25x (vs 3x in round 11, which regressed on HBM fetch).
// Window chunk = within-lane serial scans (3 ops) + 16-lane row scans via DPP
// row_shl/row_shr 1,2,4,8 + exclusive shift with identity (verified r7/r10/r11).
// Boundaries: clamped scalar path (q<0 -> -inf, q<63 -> prev_input,
// q>4158 -> -inf; fake tail values never reach valid outputs). Segment S==0
// overrides M_0[0..62] with prev_max_out; M_0[63] = mid[0] falls out of the
// clamped scan automatically.

#define TT    4096
#define PADN  63
#define XPMAX 4158   // last valid xpad index
#define SEG   512    // outputs per 16-lane row
#define NSL   10     // slabs per segment
#define NM    9      // stage-1 windows per segment
#define NCH   8      // output chunks per segment

// 4-byte-aligned float4 for unaligned-by-one global vector loads.
struct __attribute__((packed, aligned(4))) f4u { float x, y, z, w; };

template<int CTRL>
__device__ __forceinline__ float dpp_self(float v) {
  return __int_as_float(__builtin_amdgcn_update_dpp(
      __float_as_int(v), __float_as_int(v), CTRL, 0xF, 0xF, false));
}
template<int CTRL>
__device__ __forceinline__ float dpp_old(float oldv, float v) {
  return __int_as_float(__builtin_amdgcn_update_dpp(
      __float_as_int(oldv), __float_as_int(v), CTRL, 0xF, 0xF, false));
}

// 64-wide sliding window over [a0 | a1] for one 16-lane row: r[k] = OP over
// window starting at j = 4*l16 + k.  (verified rounds 7/10/11)
template<bool IS_MAX>
__device__ __forceinline__ void chunk_windows(float4 a0, float4 a1, float r[4]) {
  const float ID = IS_MAX ? -INFINITY : INFINITY;
#define OPF(x, y) (IS_MAX ? fmaxf((x), (y)) : fminf((x), (y)))
  // within-lane suffix scan of a0
  float s3 = a0.w;
  float s2 = OPF(a0.z, s3);
  float s1 = OPF(a0.y, s2);
  float s0 = OPF(a0.x, s1);
  // row inclusive suffix scan of lane totals (row_shl:d = lane i <- i+d)
  float t = s0;
  t = OPF(t, dpp_self<0x101>(t));
  t = OPF(t, dpp_self<0x102>(t));
  t = OPF(t, dpp_self<0x104>(t));
  t = OPF(t, dpp_self<0x108>(t));
  float E = dpp_old<0x101>(ID, t);   // exclusive lane-suffix (l16==15 -> ID)

  // within-lane prefix scan of a1
  float p0 = a1.x;
  float p1 = OPF(p0, a1.y);
  float p2 = OPF(p1, a1.z);
  float p3 = OPF(p2, a1.w);
  float u = p3;
  u = OPF(u, dpp_self<0x111>(u));    // row_shr:d = lane i <- i-d
  u = OPF(u, dpp_self<0x112>(u));
  u = OPF(u, dpp_self<0x114>(u));
  u = OPF(u, dpp_self<0x118>(u));
  float Ep = dpp_old<0x111>(ID, u);  // exclusive lane-prefix (l16==0 -> ID)

  r[0] = OPF(OPF(s0, E), Ep);
  r[1] = OPF(OPF(s1, E), OPF(Ep, p0));
  r[2] = OPF(OPF(s2, E), OPF(Ep, p1));
  r[3] = OPF(OPF(s3, E), OPF(Ep, p2));
#undef OPF
}

// xpad slab [t0 .. t0+63], this lane's 4 elems at t0 + 4*l16 .. +3.
__device__ __forceinline__ float4 load_slab(int t0, int l16,
                                            const float* __restrict__ xrow,
                                            const float* __restrict__ pirow) {
  if (t0 >= PADN && t0 <= TT - 1) {  // slab fully inside x
    f4u v = *reinterpret_cast<const f4u*>(xrow + t0 - PADN + 4 * l16);
    return make_float4(v.x, v.y, v.z, v.w);
  }
  float e[4];
  #pragma unroll
  for (int k = 0; k < 4; ++k) {
    const int q = t0 + 4 * l16 + k;
    float v;
    if (q < 0)           v = -INFINITY;     // before stream start
    else if (q < PADN)   v = pirow[q];      // prev_input pad
    else if (q <= XPMAX) v = xrow[q - PADN];
    else                 v = -INFINITY;     // past row end (never consumed)
    e[k] = v;
  }
  return make_float4(e[0], e[1], e[2], e[3]);
}

__global__ __launch_bounds__(256)
void mmh_kernel(const float* __restrict__ x,
                const float* __restrict__ prev_input,
                const float* __restrict__ prev_max_out,
                float* __restrict__ out)
{
    const int tid  = threadIdx.x;
    const int l16  = tid & 15;
    const int rid  = blockIdx.x * 16 + (tid >> 4);  // global segment id
    const int trow = rid >> 3;                      // [B*C] row
    const int S    = (rid & 7) * SEG;               // segment output base

    const float* xrow  = x            + (size_t)trow * TT;
    const float* pirow = prev_input   + (size_t)trow * PADN;
    const float* pmrow = prev_max_out + (size_t)trow * PADN;
    float*       orow  = out          + (size_t)trow * TT;

    // ---- all 10 slab loads issued up-front (independent; MLP) ----
    float4 L[NSL];
    #pragma unroll
    for (int j = 0; j < NSL; ++j)
        L[j] = load_slab(S - 63 + 64 * j, l16, xrow, pirow);

    // ---- stage 1: 9 sliding-max windows -> mpad slabs @(S+64j) ----
    float M[NM][4];
    #pragma unroll
    for (int j = 0; j < NM; ++j)
        chunk_windows<true>(L[j], L[j + 1], M[j]);

    if (S == 0) {
        // mpad[0..62] = prev_max_out; mpad[63] = mid[0] (already in M[0])
        #pragma unroll
        for (int k = 0; k < 4; ++k) {
            const int p = 4 * l16 + k;
            if (p < PADN) M[0][k] = pmrow[p];
        }
    }

    // ---- stage 2: 8 sliding-min windows -> out[S .. S+511] ----
    #pragma unroll
    for (int j = 0; j < NCH; ++j) {
        const float4 a0 = make_float4(M[j][0], M[j][1], M[j][2], M[j][3]);
        const float4 a1 = make_float4(M[j + 1][0], M[j + 1][1], M[j + 1][2], M[j + 1][3]);
        float r[4];
        chunk_windows<false>(a0, a1, r);
        *reinterpret_cast<float4*>(orow + S + 64 * j + 4 * l16) =
            make_float4(r[0], r[1], r[2], r[3]);
    }
}

extern "C" void kernel_launch(void* const* d_in, const int* in_sizes, int n_in,
                              void* d_out, int out_size, void* d_ws, size_t ws_size,
                              hipStream_t stream) {
    const float* x            = (const float*)d_in[0];  // [64,64,4096]
    const float* prev_input   = (const float*)d_in[1];  // [64,64,63]
    const float* prev_max_out = (const float*)d_in[2];  // [64,64,63]
    float*       out          = (float*)d_out;          // [64,64,4096]

    // 16 segments per 256-thread block; 64*64 rows x 8 segments / 16 = 2048 blocks.
    mmh_kernel<<<2048, 256, 0, stream>>>(x, prev_input, prev_max_out, out);
}